// Round 1
// baseline (57.465 us; speedup 1.0000x reference)
//
#include <hip/hip_runtime.h>

#define VOCAB 32000
#define NST 10
#define NLBL 50
#define BATCH 256
#define TLEN 1024
#define EPAD 12
#define LC 32
#define NC 32
#define HALO 16
#define LN2F 0.69314718055994531f

static __device__ __forceinline__ int imax(int a, int b) { return a > b ? a : b; }
static __device__ __forceinline__ int imin(int a, int b) { return a < b ? a : b; }

static __device__ __forceinline__ float bperm(int idx4, float v) {
    return __int_as_float(__builtin_amdgcn_ds_bpermute(idx4, __float_as_int(v)));
}

// ---------------- emission (+params in block 0) kernel ----------------
// ws layout (floats): [0..99] T row-softmax, [100..199] T^T, [200..699] O row-softmax,
//                     [1024 ..) E[B*T][EPAD]  (needs ~12.6 MB of ws)
__global__ __launch_bounds__(256) void k_emis(const int* __restrict__ sent,
                                              const float* __restrict__ W,
                                              const float* __restrict__ trans,
                                              const float* __restrict__ outw,
                                              float* __restrict__ ws) {
    if (blockIdx.x == 0) {
        int tid = threadIdx.x;
        if (tid < NST) {
            float m = -1e30f;
            for (int j = 0; j < NST; ++j) m = fmaxf(m, trans[tid * NST + j]);
            float s = 0.f;
            for (int j = 0; j < NST; ++j) s += __expf(trans[tid * NST + j] - m);
            float inv = 1.f / s;
            for (int j = 0; j < NST; ++j) {
                float v = __expf(trans[tid * NST + j] - m) * inv;
                ws[tid * NST + j] = v;          // T[i][j]
                ws[100 + j * NST + tid] = v;    // Tt[j][i] = T[i][j]
            }
        }
        if (tid >= 32 && tid < 32 + NST) {
            int i = tid - 32;
            float m = -1e30f;
            for (int l = 0; l < NLBL; ++l) m = fmaxf(m, outw[i * NLBL + l]);
            float s = 0.f;
            for (int l = 0; l < NLBL; ++l) s += __expf(outw[i * NLBL + l] - m);
            float inv = 1.f / s;
            for (int l = 0; l < NLBL; ++l)
                ws[200 + i * NLBL + l] = __expf(outw[i * NLBL + l] - m) * inv;
        }
    }

    int idx = blockIdx.x * 256 + threadIdx.x;   // < BATCH*TLEN
    int tok = sent[idx];
    const float2* w2 = reinterpret_cast<const float2*>(W + (size_t)tok * NST);
    float2 a0 = w2[0], a1 = w2[1], a2 = w2[2], a3 = w2[3], a4 = w2[4];
    float r[10] = {a0.x, a0.y, a1.x, a1.y, a2.x, a2.y, a3.x, a3.y, a4.x, a4.y};
    float m = r[0];
    #pragma unroll
    for (int j = 1; j < 10; ++j) m = fmaxf(m, r[j]);
    float s = 0.f;
    #pragma unroll
    for (int j = 0; j < 10; ++j) { r[j] = __expf(r[j] - m); s += r[j]; }
    float inv = 1.f / s;
    float4* o = reinterpret_cast<float4*>(ws + 1024 + (size_t)idx * EPAD);
    o[0] = make_float4(r[0] * inv, r[1] * inv, r[2] * inv, r[3] * inv);
    o[1] = make_float4(r[4] * inv, r[5] * inv, r[6] * inv, r[7] * inv);
    o[2] = make_float4(r[8] * inv, r[9] * inv, 0.f, 0.f);
}

// ---------------- fused chunked forward/backward + combine ----------------
__global__ __launch_bounds__(256, 2) void k_scan(const float* __restrict__ ws,
                                                 float* __restrict__ out) {
    const float* Tm = ws;
    const float* Tt = ws + 100;
    const float* Om = ws + 200;
    const float* E  = ws + 1024;

    __shared__ float ahist[16][LC][EPAD];   // 24 KB

    const int tid = threadIdx.x;
    const int sub = tid & 15;
    const int gIn = tid >> 4;               // 0..15 groups per block
    const int gid = blockIdx.x * 16 + gIn;  // 0..8191
    const int b = gid >> 5;
    const int c = gid & (NC - 1);
    const int t0 = c * LC;

    const int row = (sub < NST) ? sub : 0;

    float vT[10], vTt[10];
    #pragma unroll
    for (int j = 0; j < 10; ++j) { vT[j] = Tm[row * 10 + j]; vTt[j] = Tt[row * 10 + j]; }

    float vO[4][10];
    #pragma unroll
    for (int m = 0; m < 4; ++m) {
        int l = sub + 16 * m;
        bool ok = (l < NLBL);
        #pragma unroll
        for (int j = 0; j < 10; ++j) vO[m][j] = ok ? Om[j * NLBL + l] : 0.f;
    }

    const int base = tid & 48;              // 16-lane group base within wave
    int idxg[10];
    #pragma unroll
    for (int j = 0; j < 10; ++j) idxg[j] = (base + j) * 4;
    int rotidx[4];
    rotidx[0] = (base + (sub + 1) % 10) * 4;
    rotidx[1] = (base + (sub + 2) % 10) * 4;
    rotidx[2] = (base + (sub + 4) % 10) * 4;
    rotidx[3] = (base + (sub + 8) % 10) * 4;

    const float* Eb = E + (size_t)b * TLEN * EPAD;
    float* hist = &ahist[gIn][0][0];

    // ---------------- forward (halo + chunk, store alpha history) ----------------
    {
        const int hs = t0 - HALO;           // may be negative only for c==0
        float ecur[8], enext[8];
        #pragma unroll
        for (int i = 0; i < 8; ++i) ecur[i] = Eb[imax(hs + i, 0) * EPAD + row];
        float alpha = ecur[0];              // alpha at position max(hs,0)
        #pragma unroll
        for (int i = 0; i < 8; ++i) enext[i] = Eb[imax(hs + 8 + i, 0) * EPAD + row];

        // block 0: steps k=1..7 (pure halo)
        #pragma unroll
        for (int i = 1; i < 8; ++i) {
            int p = hs + i;
            float acc0 = 0.f, acc1 = 0.f;
            #pragma unroll
            for (int j = 0; j < 10; ++j) {
                float aj = bperm(idxg[j], alpha);
                if (j & 1) acc1 = fmaf(vT[j], aj, acc1);
                else       acc0 = fmaf(vT[j], aj, acc0);
            }
            float an = (acc0 + acc1) * ecur[i];
            alpha = (p >= 1) ? an : alpha;   // c==0: keep alpha_0 = E_0 for p<=0
            if ((i & 3) == 3) {
                float mx = alpha;
                #pragma unroll
                for (int r = 0; r < 4; ++r) mx = fmaxf(mx, bperm(rotidx[r], mx));
                alpha *= __builtin_amdgcn_rcpf(mx);
            }
        }
        #pragma unroll
        for (int i = 0; i < 8; ++i) ecur[i] = enext[i];

        for (int mblk = 1; mblk < 6; ++mblk) {
            if (mblk < 5) {
                #pragma unroll
                for (int i = 0; i < 8; ++i)
                    enext[i] = Eb[imax(hs + 8 * (mblk + 1) + i, 0) * EPAD + row];
            }
            #pragma unroll
            for (int i = 0; i < 8; ++i) {
                int k = 8 * mblk + i;
                int p = hs + k;
                float acc0 = 0.f, acc1 = 0.f;
                #pragma unroll
                for (int j = 0; j < 10; ++j) {
                    float aj = bperm(idxg[j], alpha);
                    if (j & 1) acc1 = fmaf(vT[j], aj, acc1);
                    else       acc0 = fmaf(vT[j], aj, acc0);
                }
                float an = (acc0 + acc1) * ecur[i];
                alpha = (p >= 1) ? an : alpha;
                if (mblk >= 2) {                       // k>=16: inside chunk -> store
                    if (sub < NST) hist[(k - HALO) * EPAD + sub] = alpha;
                }
                if ((i & 3) == 3) {
                    float mx = alpha;
                    #pragma unroll
                    for (int r = 0; r < 4; ++r) mx = fmaxf(mx, bperm(rotidx[r], mx));
                    alpha *= __builtin_amdgcn_rcpf(mx);
                }
            }
            #pragma unroll
            for (int i = 0; i < 8; ++i) ecur[i] = enext[i];
        }
    }

    // ---------------- backward (halo + chunk) with fused combine + output ----------------
    {
        const int pe = t0 + LC - 1 + HALO;  // virtual start position (k=0)
        float ecur[8], enext[8];
        #pragma unroll
        for (int i = 0; i < 8; ++i) ecur[i] = Eb[imin(pe - i, TLEN - 1) * EPAD + row];
        float g = ecur[0];                   // init g (exact iff clamped to T-1 boundary)
        #pragma unroll
        for (int i = 0; i < 8; ++i) enext[i] = Eb[imin(pe - 8 - i, TLEN - 1) * EPAD + row];

        #pragma unroll
        for (int i = 1; i < 8; ++i) {
            int p = pe - i;
            float acc0 = 0.f, acc1 = 0.f;
            #pragma unroll
            for (int j = 0; j < 10; ++j) {
                float gj = bperm(idxg[j], g);
                if (j & 1) acc1 = fmaf(vTt[j], gj, acc1);
                else       acc0 = fmaf(vTt[j], gj, acc0);
            }
            float u = acc0 + acc1;
            u = (p == TLEN - 1) ? 1.f : u;   // t=T-1: backwards includes only emission
            float gn = ecur[i] * u;
            g = (p > TLEN - 1) ? g : gn;     // virtual positions: keep init
            if ((i & 3) == 3) {
                float mx = g;
                #pragma unroll
                for (int r = 0; r < 4; ++r) mx = fmaxf(mx, bperm(rotidx[r], mx));
                g *= __builtin_amdgcn_rcpf(mx);
            }
        }
        #pragma unroll
        for (int i = 0; i < 8; ++i) ecur[i] = enext[i];

        for (int mblk = 1; mblk < 6; ++mblk) {
            if (mblk < 5) {
                #pragma unroll
                for (int i = 0; i < 8; ++i)
                    enext[i] = Eb[imin(pe - 8 * (mblk + 1) - i, TLEN - 1) * EPAD + row];
            }
            #pragma unroll
            for (int i = 0; i < 8; ++i) {
                int k = 8 * mblk + i;
                int p = pe - k;
                float acc0 = 0.f, acc1 = 0.f;
                #pragma unroll
                for (int j = 0; j < 10; ++j) {
                    float gj = bperm(idxg[j], g);
                    if (j & 1) acc1 = fmaf(vTt[j], gj, acc1);
                    else       acc0 = fmaf(vTt[j], gj, acc0);
                }
                float u = acc0 + acc1;
                u = (p == TLEN - 1) ? 1.f : u;
                if (mblk >= 2) {                 // k>=16: p in [t0, t0+LC) -> emit outputs
                    float pr = 0.f;
                    if (sub < NST) pr = hist[(p - t0) * EPAD + sub] * u;  // alpha*u (E cancels)
                    float pv[10];
                    #pragma unroll
                    for (int j = 0; j < 10; ++j) pv[j] = bperm(idxg[j], pr);
                    float sm = ((pv[0] + pv[1]) + (pv[2] + pv[3])) +
                               ((pv[4] + pv[5]) + (pv[6] + pv[7])) + (pv[8] + pv[9]);
                    float ls = __log2f(sm);
                    float* orow = out + ((size_t)b * TLEN + p) * NLBL;
                    #pragma unroll
                    for (int m = 0; m < 4; ++m) {
                        float d = 0.f;
                        #pragma unroll
                        for (int j = 0; j < 10; ++j) d = fmaf(pv[j], vO[m][j], d);
                        float val = (__log2f(d) - ls) * LN2F;
                        int l = sub + 16 * m;
                        if (l < NLBL) orow[l] = val;
                    }
                }
                float gn = ecur[i] * u;
                g = (p > TLEN - 1) ? g : gn;
                if ((i & 3) == 3) {
                    float mx = g;
                    #pragma unroll
                    for (int r = 0; r < 4; ++r) mx = fmaxf(mx, bperm(rotidx[r], mx));
                    g *= __builtin_amdgcn_rcpf(mx);
                }
            }
            #pragma unroll
            for (int i = 0; i < 8; ++i) ecur[i] = enext[i];
        }
    }
}

extern "C" void kernel_launch(void* const* d_in, const int* in_sizes, int n_in,
                              void* d_out, int out_size, void* d_ws, size_t ws_size,
                              hipStream_t stream) {
    const int*   sent  = (const int*)d_in[0];
    const float* W     = (const float*)d_in[1];
    const float* trans = (const float*)d_in[2];
    const float* outw  = (const float*)d_in[3];
    float* ws  = (float*)d_ws;   // needs ~12.6 MB
    float* out = (float*)d_out;

    hipLaunchKernelGGL(k_emis, dim3((BATCH * TLEN) / 256), dim3(256), 0, stream,
                       sent, W, trans, outw, ws);
    hipLaunchKernelGGL(k_scan, dim3((BATCH * NC) / 16), dim3(256), 0, stream, ws, out);
}

// Round 2
// 43.457 us; speedup vs baseline: 1.3223x; 1.3223x over previous
//
#include <hip/hip_runtime.h>

#define NST 10
#define NLBL 50
#define BATCH 256
#define TLEN 1024
#define TPB 512
#define HALO 8
#define ROWS (TPB + 2*HALO)   // 528
#define EPAD 13
#define PRPAD 13
#define SC 1.0e15f
#define LN2F 0.69314718055994531f

__global__ __launch_bounds__(256, 2) void k_all(const int* __restrict__ sent,
                                                const float* __restrict__ W,
                                                const float* __restrict__ trans,
                                                const float* __restrict__ outw,
                                                float* __restrict__ out) {
    __shared__ alignas(16) float Elds[ROWS][EPAD];   // 27.5 KB
    __shared__ alignas(16) float prl[TPB][PRPAD];    // 26.6 KB
    __shared__ alignas(16) float Tl[112];
    __shared__ alignas(16) float Ttl[112];
    __shared__ alignas(16) float Ol[NST][56];

    const int tid = threadIdx.x;
    const int b   = (int)blockIdx.x >> 1;
    const int tb  = ((int)blockIdx.x & 1) * TPB;

    // ---- parameter prep (redundant per block; cheap) ----
    if (tid < NST) {
        float r[NST]; float m = -1e30f, s = 0.f;
        #pragma unroll
        for (int j = 0; j < NST; ++j) { r[j] = trans[tid*NST + j]; m = fmaxf(m, r[j]); }
        #pragma unroll
        for (int j = 0; j < NST; ++j) { r[j] = __expf(r[j] - m); s += r[j]; }
        float inv = 1.f / s;
        #pragma unroll
        for (int j = 0; j < NST; ++j) { Tl[tid*NST + j] = r[j]*inv; Ttl[j*NST + tid] = r[j]*inv; }
    } else if (tid >= 32 && tid < 32 + NST) {
        const int i = tid - 32;
        float m = -1e30f, s = 0.f; float r[NLBL];
        for (int l = 0; l < NLBL; ++l) { r[l] = outw[i*NLBL + l]; m = fmaxf(m, r[l]); }
        for (int l = 0; l < NLBL; ++l) { r[l] = __expf(r[l] - m); s += r[l]; }
        float inv = 1.f / s;
        for (int l = 0; l < NLBL; ++l) Ol[i][l] = r[l]*inv;
        for (int l = NLBL; l < 56; ++l) Ol[i][l] = 0.f;
    }

    // ---- emission staging: gather W[tok], softmax, -> LDS ----
    const int* sb = sent + b*TLEN;
    for (int r = tid; r < ROWS; r += 256) {
        int p  = tb - HALO + r;
        int pc = min(max(p, 0), TLEN-1);
        int tok = sb[pc];
        const float2* w2 = reinterpret_cast<const float2*>(W + (size_t)tok*NST);
        float2 q0=w2[0], q1=w2[1], q2=w2[2], q3=w2[3], q4=w2[4];
        float e[10] = {q0.x,q0.y,q1.x,q1.y,q2.x,q2.y,q3.x,q3.y,q4.x,q4.y};
        float m = e[0];
        #pragma unroll
        for (int j=1;j<10;++j) m = fmaxf(m, e[j]);
        float s = 0.f;
        #pragma unroll
        for (int j=0;j<10;++j) { e[j] = __expf(e[j]-m); s += e[j]; }
        float inv = 1.f/s;
        #pragma unroll
        for (int j=0;j<10;++j) Elds[r][j] = e[j]*inv;
    }
    __syncthreads();

    const int t0  = tb + 2*tid;     // this thread's chunk = {t0, t0+1}
    const int lr0 = 2*tid;          // LDS row of global position t0-HALO

    float vT[100];
    #pragma unroll
    for (int k=0;k<100;++k) vT[k] = Tl[k];

    // ---- forward: 9 steps from t0-HALO, keep alpha(t0), alpha(t0+1) ----
    float alpha[10], a0s[10], a1s[10];
    #pragma unroll
    for (int s=0;s<10;++s) alpha[s] = Elds[lr0][s] * SC;

    #pragma unroll
    for (int i=1;i<=HALO+1;++i) {
        const int p = t0 - HALO + i;
        float an[10];
        #pragma unroll
        for (int s=0;s<10;++s) {
            float acc = 0.f;
            #pragma unroll
            for (int j=0;j<10;++j) acc = fmaf(vT[s*10+j], alpha[j], acc);
            an[s] = acc * Elds[lr0+i][s];
        }
        const bool upd = (p >= 1);
        #pragma unroll
        for (int s=0;s<10;++s) alpha[s] = upd ? an[s] : alpha[s];
        if (i == HALO) {
            #pragma unroll
            for (int s=0;s<10;++s) a0s[s] = alpha[s];
        }
    }
    #pragma unroll
    for (int s=0;s<10;++s) a1s[s] = alpha[s];

    // ---- backward: 9 steps from t0+HALO+1 down to t0; fuse posterior ----
    #pragma unroll
    for (int k=0;k<100;++k) vT[k] = Ttl[k];   // now holds T^T

    float g[10];
    const int lre = 2*tid + 2*HALO + 1;       // LDS row of t0+HALO+1 (clamped data)
    #pragma unroll
    for (int s=0;s<10;++s) g[s] = Elds[lre][s] * SC;

    #pragma unroll
    for (int i=1;i<=HALO+1;++i) {
        const int p = t0 + HALO + 1 - i;
        float u[10];
        #pragma unroll
        for (int s=0;s<10;++s) {
            float acc = 0.f;
            #pragma unroll
            for (int j=0;j<10;++j) acc = fmaf(vT[s*10+j], g[j], acc);
            u[s] = acc;
        }
        const bool last = (p == TLEN-1);
        #pragma unroll
        for (int s=0;s<10;++s) u[s] = last ? SC : u[s];
        if (i == HALO) {          // p == t0+1
            float sum = 0.f; float pr[10];
            #pragma unroll
            for (int s=0;s<10;++s) { pr[s] = a1s[s]*u[s]; sum += pr[s]; }
            #pragma unroll
            for (int s=0;s<10;++s) prl[2*tid+1][s] = pr[s];
            prl[2*tid+1][10] = __log2f(sum);
        }
        if (i == HALO+1) {        // p == t0
            float sum = 0.f; float pr[10];
            #pragma unroll
            for (int s=0;s<10;++s) { pr[s] = a0s[s]*u[s]; sum += pr[s]; }
            #pragma unroll
            for (int s=0;s<10;++s) prl[2*tid][s] = pr[s];
            prl[2*tid][10] = __log2f(sum);
        }
        const bool keep = (p > TLEN-1);
        #pragma unroll
        for (int s=0;s<10;++s) {
            float gn = Elds[lre - i][s] * u[s];
            g[s] = keep ? g[s] : gn;
        }
    }
    __syncthreads();

    // ---- combine: out[t][l] = (log2(dot(pr, O[:,l])) - log2(sum pr)) * ln2 ----
    const int lg = tid & 7;
    const int tq = tid >> 3;
    const int lb = lg * 7;                    // labels lb..lb+6 (masked at 50)
    float vO[10][7];
    #pragma unroll
    for (int s=0;s<10;++s)
        #pragma unroll
        for (int k=0;k<7;++k) vO[s][k] = Ol[s][lb+k];

    float* ob = out + ((size_t)b*TLEN + tb)*NLBL;
    for (int it=0; it<16; ++it) {
        const int t = tq + 32*it;
        float pv[10];
        #pragma unroll
        for (int s=0;s<10;++s) pv[s] = prl[t][s];
        const float ls = prl[t][10];
        float* orow = ob + t*NLBL + lb;
        #pragma unroll
        for (int k=0;k<7;++k) {
            float d = 0.f;
            #pragma unroll
            for (int s=0;s<10;++s) d = fmaf(pv[s], vO[s][k], d);
            float v = (__log2f(d) - ls) * LN2F;
            if (lb + k < NLBL) orow[k] = v;
        }
    }
}

extern "C" void kernel_launch(void* const* d_in, const int* in_sizes, int n_in,
                              void* d_out, int out_size, void* d_ws, size_t ws_size,
                              hipStream_t stream) {
    const int*   sent  = (const int*)d_in[0];
    const float* W     = (const float*)d_in[1];
    const float* trans = (const float*)d_in[2];
    const float* outw  = (const float*)d_in[3];
    float* out = (float*)d_out;

    hipLaunchKernelGGL(k_all, dim3(BATCH * (TLEN / TPB)), dim3(256), 0, stream,
                       sent, W, trans, outw, out);
}